// Round 6
// baseline (306.195 us; speedup 1.0000x reference)
//
#include <hip/hip_runtime.h>
#include <hip/hip_bf16.h>
#include <hip/hip_cooperative_groups.h>
#include <math.h>

namespace cg = cooperative_groups;

// Problem constants
#define N_T   16
#define BSZ   128
#define DDIM  4096
#define KROWS (N_T * BSZ)          // 2048
#define CHW   (3 * 64 * 64)        // 12288
#define S_PIC (BSZ * CHW)          // 1572864
#define T_MSE (N_T * S_PIC)        // 25165824
#define KPOS  (KROWS * (N_T - 1))  // 30720

#define COOP_BLOCKS 512            // 2 blocks/CU x 256 CUs -- provably co-resident
#define GEMM_BLOCKS 512            // 16 x 16 tiles x split-K 2 (fallback mega grid)
#define MSE_JOBS    3072           // 16 slabs x 192 jobs

typedef short  bf16x8 __attribute__((ext_vector_type(8)));   // 8 bf16 = 4 VGPRs
typedef float  f32x4  __attribute__((ext_vector_type(4)));

// ---------------- reductions ----------------
// Called multiple times per block: leading __syncthreads() protects the
// shared scratch from the previous call.
__device__ __forceinline__ float waveReduceSum(float v) {
    for (int off = 32; off > 0; off >>= 1) v += __shfl_down(v, off, 64);
    return v;
}
__device__ __forceinline__ float waveReduceMax(float v) {
    for (int off = 32; off > 0; off >>= 1) v = fmaxf(v, __shfl_down(v, off, 64));
    return v;
}
__device__ __forceinline__ float blockReduceSum(float v) {
    __shared__ float s[8];
    int lane = threadIdx.x & 63, wid = threadIdx.x >> 6;
    v = waveReduceSum(v);
    __syncthreads();
    if (lane == 0) s[wid] = v;
    __syncthreads();
    int nw = (blockDim.x + 63) >> 6;
    v = (threadIdx.x < nw) ? s[threadIdx.x] : 0.0f;
    if (wid == 0) v = waveReduceSum(v);
    return v;   // valid in thread 0
}
__device__ __forceinline__ float blockReduceMax(float v) {
    __shared__ float s[8];
    int lane = threadIdx.x & 63, wid = threadIdx.x >> 6;
    v = waveReduceMax(v);
    __syncthreads();
    if (lane == 0) s[wid] = v;
    __syncthreads();
    int nw = (blockDim.x + 63) >> 6;
    v = (threadIdx.x < nw) ? s[threadIdx.x] : -INFINITY;
    if (wid == 0) v = waveReduceMax(v);
    return v;   // valid in thread 0
}

// ---------------- device bodies ----------------
// MSE slab-chunk: 8192 contiguous floats at n*S_PIC + bx*8192 (m13 pattern).
__device__ __forceinline__ float mse_chunk(const float* __restrict__ pic,
                                           const float* __restrict__ dec,
                                           int n, int bx) {
    const size_t off = (size_t)n * S_PIC + (size_t)bx * 8192 + threadIdx.x * 4;
    const ptrdiff_t doff = (ptrdiff_t)(((n + 1) & (N_T - 1)) - n) * S_PIC;
    const float* p = pic + off;
    const float* d = dec + off + doff;
    float s0 = 0.f, s1 = 0.f, s2 = 0.f, s3 = 0.f;
#pragma unroll
    for (int k = 0; k < 8; k++) {
        float4 a = *(const float4*)(p + k * 1024);
        float4 b = *(const float4*)(d + k * 1024);
        float dx = a.x - b.x, dy = a.y - b.y, dz = a.z - b.z, dw = a.w - b.w;
        s0 += dx * dx; s1 += dy * dy; s2 += dz * dz; s3 += dw * dw;
    }
    return (s0 + s1) + (s2 + s3);
}

// Normalize one row of h (fp32, DDIM) into bf16 hbuf. Block-cooperative.
__device__ __forceinline__ void norm_row(const float* __restrict__ h,
                                         __hip_bfloat16* __restrict__ hb, int row) {
    const float* r = h + (size_t)row * DDIM;
    float ss = 0.0f;
#pragma unroll
    for (int k = threadIdx.x * 8; k < DDIM; k += 2048) {
        float4 v0 = *(const float4*)(r + k);
        float4 v1 = *(const float4*)(r + k + 4);
        ss += v0.x * v0.x + v0.y * v0.y + v0.z * v0.z + v0.w * v0.w;
        ss += v1.x * v1.x + v1.y * v1.y + v1.z * v1.z + v1.w * v1.w;
    }
    ss = blockReduceSum(ss);
    __shared__ float scale_s;
    if (threadIdx.x == 0) scale_s = 1.0f / fmaxf(sqrtf(ss), 1e-8f);
    __syncthreads();
    const float sc = scale_s;
    __hip_bfloat16* ob = hb + (size_t)row * DDIM;
#pragma unroll
    for (int k = threadIdx.x * 8; k < DDIM; k += 2048) {
        float4 v0 = *(const float4*)(r + k);
        float4 v1 = *(const float4*)(r + k + 4);
        __hip_bfloat16 t[8];
        t[0] = __float2bfloat16(v0.x * sc); t[1] = __float2bfloat16(v0.y * sc);
        t[2] = __float2bfloat16(v0.z * sc); t[3] = __float2bfloat16(v0.w * sc);
        t[4] = __float2bfloat16(v1.x * sc); t[5] = __float2bfloat16(v1.y * sc);
        t[6] = __float2bfloat16(v1.z * sc); t[7] = __float2bfloat16(v1.w * sc);
        *(bf16x8*)(ob + k) = *(const bf16x8*)t;   // 16 B store
    }
}

// m97-structure GEMM tile job (kz, bi, bj): 128x128 output tile of
// Cpart[kz] = 2 * X[:,khalf] @ X[:,khalf]^T. lds = 16 KB (As | Bs).
__device__ __forceinline__ void gemm_tile(const ushort* __restrict__ X,
                                          float* __restrict__ Cpart,
                                          ushort* lds, int kz, int bi, int bj) {
    ushort* As = lds;            // 128 x 32 row-major
    ushort* Bs = lds + 4096;
    const int tid  = threadIdx.x;
    const int wave = tid >> 6, lane = tid & 63;
    const int wm = wave >> 1, wn = wave & 1;        // 2x2 wave grid
    const int quad = lane >> 4, l16 = lane & 15;

    f32x4 acc_r[4][4];
#pragma unroll
    for (int i = 0; i < 4; i++)
#pragma unroll
        for (int j = 0; j < 4; j++) acc_r[i][j] = (f32x4){0.f, 0.f, 0.f, 0.f};

    // Staging: 8 chunks of 16 rows per tile; wave w loads chunks {w, w+4}.
    // LDS dest is wave-uniform base + lane*16 B (global_load_lds semantics).
    const int srow = lane >> 2;          // 0..15
    const int scol = (lane & 3) * 8;     // 0,8,16,24
    const ushort* Ag0 = X + (size_t)(bi * 128 + wave * 16       + srow) * DDIM + scol;
    const ushort* Ag1 = X + (size_t)(bi * 128 + (wave + 4) * 16 + srow) * DDIM + scol;
    const ushort* Bg0 = X + (size_t)(bj * 128 + wave * 16       + srow) * DDIM + scol;
    const ushort* Bg1 = X + (size_t)(bj * 128 + (wave + 4) * 16 + srow) * DDIM + scol;
    ushort* Al0 = As + wave * 512;
    ushort* Al1 = As + (wave + 4) * 512;
    ushort* Bl0 = Bs + wave * 512;
    ushort* Bl1 = Bs + (wave + 4) * 512;

    const int k0 = kz * (DDIM / 2), k1 = k0 + (DDIM / 2);
    for (int kk = k0; kk < k1; kk += 32) {
        __syncthreads();   // previous iter's LDS reads done before overwrite
        __builtin_amdgcn_global_load_lds(
            (const __attribute__((address_space(1))) unsigned int*)(Ag0 + kk),
            (__attribute__((address_space(3))) unsigned int*)Al0, 16, 0, 0);
        __builtin_amdgcn_global_load_lds(
            (const __attribute__((address_space(1))) unsigned int*)(Ag1 + kk),
            (__attribute__((address_space(3))) unsigned int*)Al1, 16, 0, 0);
        __builtin_amdgcn_global_load_lds(
            (const __attribute__((address_space(1))) unsigned int*)(Bg0 + kk),
            (__attribute__((address_space(3))) unsigned int*)Bl0, 16, 0, 0);
        __builtin_amdgcn_global_load_lds(
            (const __attribute__((address_space(1))) unsigned int*)(Bg1 + kk),
            (__attribute__((address_space(3))) unsigned int*)Bl1, 16, 0, 0);
        __syncthreads();   // drains vmcnt(0): staging visible

        bf16x8 a[4], b[4];
#pragma unroll
        for (int t = 0; t < 4; t++)   // A[m = l16 + tile][k = quad*8 + 0..7]
            a[t] = *(const bf16x8*)(As + (wm * 64 + t * 16 + l16) * 32 + quad * 8);
#pragma unroll
        for (int t = 0; t < 4; t++)
            b[t] = *(const bf16x8*)(Bs + (wn * 64 + t * 16 + l16) * 32 + quad * 8);
#pragma unroll
        for (int mt = 0; mt < 4; mt++)
#pragma unroll
            for (int nt = 0; nt < 4; nt++)
                acc_r[mt][nt] = __builtin_amdgcn_mfma_f32_16x16x32_bf16(
                    a[mt], b[nt], acc_r[mt][nt], 0, 0, 0);
    }

    // Epilogue: C/D layout col = lane&15, row = quad*4 + reg. 2*acc (the /TEMP).
    float* Cp = Cpart + (size_t)kz * KROWS * KROWS;
#pragma unroll
    for (int mt = 0; mt < 4; mt++) {
#pragma unroll
        for (int r = 0; r < 4; r++) {
            const int row = bi * 128 + wm * 64 + mt * 16 + quad * 4 + r;
            float* o = Cp + (size_t)row * KROWS + bj * 128 + wn * 64 + l16;
#pragma unroll
            for (int nt = 0; nt < 4; nt++) o[nt * 16] = 2.0f * acc_r[mt][nt][r];
        }
    }
    __syncthreads();   // LDS free for next use
}

// Masked LSE + positives for row i; returns row loss (valid on thread 0).
__device__ __forceinline__ float lse_row(const float* __restrict__ Cpart,
                                         float* srow, int i) {
    const float* r0 = Cpart + (size_t)i * KROWS;
    const float* r1 = r0 + (size_t)KROWS * KROWS;
#pragma unroll
    for (int j = threadIdx.x * 4; j < KROWS; j += 1024) {
        float4 a = *(const float4*)(r0 + j);
        float4 b = *(const float4*)(r1 + j);
        float4 s; s.x = a.x + b.x; s.y = a.y + b.y; s.z = a.z + b.z; s.w = a.w + b.w;
        *(float4*)(srow + j) = s;
    }
    __syncthreads();

    const int ires = i & (BSZ - 1);
    float m = -INFINITY;
#pragma unroll
    for (int j = threadIdx.x; j < KROWS; j += 256)
        if ((j & (BSZ - 1)) != ires) m = fmaxf(m, srow[j]);
    m = blockReduceMax(m);
    __shared__ float mS;
    if (threadIdx.x == 0) mS = m;
    __syncthreads();
    m = mS;
    float se = 0.0f;
#pragma unroll
    for (int j = threadIdx.x; j < KROWS; j += 256)
        if ((j & (BSZ - 1)) != ires) se += expf(srow[j] - m);
    se = blockReduceSum(se);

    float loss = 0.0f;
    if (threadIdx.x == 0) {
        const float neg_lse = m + logf(se);
#pragma unroll
        for (int t = 0; t < N_T; t++) {
            const int j = ires + t * BSZ;
            if (j == i) continue;
            const float x = neg_lse - srow[j];   // logaddexp(L,p)-p = softplus(L-p)
            loss += (x > 0.0f) ? (x + log1pf(expf(-x))) : log1pf(expf(x));
        }
    }
    __syncthreads();   // srow free for next row
    return loss;
}

// ---------------- Cooperative kernel: whole pipeline, 1 dispatch ----------
// 512 blocks x 256 threads, 2 blocks/CU (needs <=256 regs, <=80 KB LDS --
// we use ~140 regs / 16.4 KB, so co-residency is guaranteed; round-5's 1024
// blocks @ launch_bounds(,4) failed the runtime occupancy check: VGPR 76 +
// AGPR 64 > 128).
// P0 norm 4 rows/blk -> P1 (blk<256: 2 GEMM tiles | blk>=256: 12 MSE chunks;
// ~1 GEMM + 1 MSE block per CU = m114 MFMA/HBM overlap) -> P2 lse 4 rows/blk
// -> P3 block-0 reduction. No atomics.
__global__ __launch_bounds__(256, 2) void coop_kernel(
    const float* __restrict__ h, ushort* __restrict__ hbuf,
    float* __restrict__ Cpart, const float* __restrict__ pic,
    const float* __restrict__ dec, float* __restrict__ partials,
    float* __restrict__ out) {
    __shared__ ushort lds[128 * 32 * 2];   // 16 KB: GEMM As|Bs, lse srow alias
    cg::grid_group grid = cg::this_grid();
    const int bid = blockIdx.x;
    const int tid = threadIdx.x;

    // ---- P0: normalize rows 4*bid .. 4*bid+3 ----
#pragma unroll
    for (int r = 0; r < 4; r++) norm_row(h, (__hip_bfloat16*)hbuf, 4 * bid + r);
    grid.sync();

    // ---- P1: GEMM + MSE overlap ----
    float msesum = 0.0f;
    if (bid < 256) {
#pragma unroll
        for (int j = 0; j < 2; j++) {
            const int job = bid + 256 * j;           // 0..511
            gemm_tile(hbuf, Cpart, lds, job >> 8, (job >> 4) & 15, job & 15);
        }
    } else {
        const int b = bid - 256;                     // 0..255
#pragma unroll
        for (int k2 = 0; k2 < 12; k2++) {
            const int t = b + 256 * k2;              // 0..3071
            msesum += mse_chunk(pic, dec, t & (N_T - 1), t >> 4);
        }
    }
    {
        float s = blockReduceSum(msesum);
        if (tid == 0) partials[bid] = s;             // 0 for GEMM blocks
    }
    grid.sync();

    // ---- P2: masked LSE rows 4*bid .. 4*bid+3 ----
    {
        float* srow = (float*)lds;
        float l = 0.0f;
#pragma unroll
        for (int r = 0; r < 4; r++) l += lse_row(Cpart, srow, 4 * bid + r);
        if (tid == 0) partials[COOP_BLOCKS + bid] = l;
    }
    grid.sync();

    // ---- P3: final reduction on block 0 ----
    if (bid == 0) {
        float v = 0.0f;
#pragma unroll
        for (int j = tid; j < 2 * COOP_BLOCKS; j += 256) {
            float p = partials[j];
            v += (j < COOP_BLOCKS) ? p * (1.0f / (float)T_MSE)
                                   : p * (1.0f / (float)KPOS);
        }
        v = blockReduceSum(v);
        if (tid == 0) out[0] = v;
    }
}

// ================== fallback multi-kernel path (round-4, proven) ==========
__global__ __launch_bounds__(256) void mega_kernel(const ushort* __restrict__ X,
                                                   float* __restrict__ Cpart,
                                                   const float* __restrict__ pic,
                                                   const float* __restrict__ dec,
                                                   float* __restrict__ acc) {
    __shared__ ushort lds[128 * 32 * 2];
    const int bid = blockIdx.x;
    if (bid >= GEMM_BLOCKS) {
        const int t = bid - GEMM_BLOCKS;
        float s = mse_chunk(pic, dec, t & (N_T - 1), t >> 4);
        s = blockReduceSum(s);
        if (threadIdx.x == 0) atomicAdd(acc, s);
        return;
    }
    gemm_tile(X, Cpart, lds, bid >> 8, (bid >> 4) & 15, bid & 15);
}
__global__ __launch_bounds__(256) void mse_kernel(const float* __restrict__ pic,
                                                  const float* __restrict__ dec,
                                                  float* __restrict__ acc) {
    float s = mse_chunk(pic, dec, blockIdx.y, blockIdx.x);
    s = blockReduceSum(s);
    if (threadIdx.x == 0) atomicAdd(acc, s);
}
__global__ void norm_kernel(const float* __restrict__ h,
                            __hip_bfloat16* __restrict__ hb) {
    norm_row(h, hb, blockIdx.x);
}
__global__ void lse_kernel(const float* __restrict__ Cpart, float* __restrict__ acc) {
    __shared__ float srow[KROWS];
    float l = lse_row(Cpart, srow, blockIdx.x);
    if (threadIdx.x == 0) atomicAdd(acc + 1, l);
}
__global__ void finalize_kernel(const float* __restrict__ acc, float* __restrict__ out) {
    if (threadIdx.x == 0 && blockIdx.x == 0)
        out[0] = acc[0] / (float)T_MSE + acc[1] / (float)KPOS;
}

extern "C" void kernel_launch(void* const* d_in, const int* in_sizes, int n_in,
                              void* d_out, int out_size, void* d_ws, size_t ws_size,
                              hipStream_t stream) {
    const float* pic = (const float*)d_in[0];
    float* dec = (float*)d_in[1];
    const float* h = (const float*)d_in[2];
    float* out = (float*)d_out;

    const size_t part_bytes   = (size_t)2 * COOP_BLOCKS * sizeof(float);        // 4 KB
    const size_t hbuf_bytes   = (size_t)KROWS * DDIM * sizeof(__hip_bfloat16);  // 16 MB
    const size_t simmat_bytes = (size_t)2 * KROWS * KROWS * sizeof(float);      // 32 MB
    const size_t need = 256 + part_bytes + hbuf_bytes + simmat_bytes;

    // Deterministic, capture-safe host-side co-residency check (no stream ops).
    int dev = 0, nCU = 0, maxAct = 0;
    hipGetDevice(&dev);
    hipDeviceGetAttribute(&nCU, hipDeviceAttributeMultiprocessorCount, dev);
    hipOccupancyMaxActiveBlocksPerMultiprocessor(&maxAct, (const void*)coop_kernel,
                                                 256, 0);
    const bool coop_ok = (ws_size >= need) && ((long)maxAct * nCU >= COOP_BLOCKS);

    if (coop_ok) {
        // Single cooperative dispatch: whole pipeline, no memset/atomics.
        float*  partials = (float*)((char*)d_ws + 256);
        ushort* hbuf     = (ushort*)((char*)d_ws + 256 + part_bytes);
        float*  Cpart    = (float*)((char*)d_ws + 256 + part_bytes + hbuf_bytes);
        void* args[] = {(void*)&h, (void*)&hbuf, (void*)&Cpart, (void*)&pic,
                        (void*)&dec, (void*)&partials, (void*)&out};
        hipLaunchCooperativeKernel((const void*)coop_kernel, dim3(COOP_BLOCKS),
                                   dim3(256), args, 0, stream);
    } else if (ws_size >= need) {
        // Round-4 proven path: overlapped mega kernel + small pre/post kernels.
        float* acc = (float*)d_ws;
        float*  partials = (float*)((char*)d_ws + 256);   // unused slots
        ushort* hbuf     = (ushort*)((char*)d_ws + 256 + part_bytes);
        float*  Cpart    = (float*)((char*)d_ws + 256 + part_bytes + hbuf_bytes);
        (void)partials;
        hipMemsetAsync(d_ws, 0, 256, stream);
        norm_kernel<<<KROWS, 256, 0, stream>>>(h, (__hip_bfloat16*)hbuf);
        mega_kernel<<<GEMM_BLOCKS + MSE_JOBS, 256, 0, stream>>>(
            hbuf, Cpart, pic, dec, acc);
        lse_kernel<<<KROWS, 256, 0, stream>>>(Cpart, acc);
        finalize_kernel<<<1, 64, 0, stream>>>(acc, out);
    } else {
        // Tiny-ws fallback: dec buffer as scratch, strictly sequential.
        float* acc = (float*)d_ws;
        ushort* hbuf = (ushort*)dec;
        float* Cpart = (float*)((char*)dec + hbuf_bytes);
        hipMemsetAsync(d_ws, 0, 256, stream);
        mse_kernel<<<dim3(MSE_JOBS / N_T, N_T), 256, 0, stream>>>(pic, dec, acc);
        norm_kernel<<<KROWS, 256, 0, stream>>>(h, (__hip_bfloat16*)hbuf);
        mega_kernel<<<GEMM_BLOCKS, 256, 0, stream>>>(hbuf, Cpart, pic, dec, acc);
        lse_kernel<<<KROWS, 256, 0, stream>>>(Cpart, acc);
        finalize_kernel<<<1, 64, 0, stream>>>(acc, out);
    }
}